// Round 8
// baseline (1866.333 us; speedup 1.0000x reference)
//
#include <hip/hip_runtime.h>
#include <hip/hip_bf16.h>

typedef __attribute__((ext_vector_type(8))) short short8;
typedef __attribute__((ext_vector_type(4))) short short4v;
typedef __attribute__((ext_vector_type(4))) float f32x4;

#define NBLK 896   // 4 blocks/CU capacity (LDS 34.8KB, VGPR<=128 via launch_bounds) x 256 CU = 1024; margin 128

static inline size_t ws_align(size_t x) { return (x + 511) & ~((size_t)511); }

static __device__ inline unsigned short f2bf(float f) {
    __hip_bfloat16 h = __float2bfloat16(f);
    return __builtin_bit_cast(unsigned short, h);
}
static __device__ inline float bfbits2f(unsigned short u) {
    unsigned x = ((unsigned)u) << 16;
    return __builtin_bit_cast(float, x);
}

// ---------------- inline dtype sniffing ----------------
static __device__ inline int sniff_fp32(const unsigned short* __restrict__ w1) {
    int i = threadIdx.x & 63;
    unsigned e = (w1[2 * i] >> 7) & 0xFF;
    unsigned long long m = __ballot(e >= 100 && e <= 130);
    return (__popcll(m) < 48) ? 1 : 0;
}
static __device__ inline int sniff_is64(const unsigned int* __restrict__ ei) {
    int i = threadIdx.x & 63;
    unsigned long long m = __ballot(ei[2 * i + 1] == 0u);
    return (__popcll(m) >= 48) ? 1 : 0;
}

// ---------------- grid barrier (all NBLK blocks co-resident by construction) ----------------
// bar[0] = arrive counter, bar[1] = released phase (monotone). Zeroed by host memset each launch.
static __device__ inline void gridbar(unsigned* __restrict__ bar, unsigned phase) {
    __syncthreads();
    if (threadIdx.x == 0) {
        __threadfence();   // release: drain writes to coherence point (L2 wb for cross-XCD)
        unsigned old = __hip_atomic_fetch_add(&bar[0], 1u, __ATOMIC_ACQ_REL, __HIP_MEMORY_SCOPE_AGENT);
        if (old == (unsigned)(gridDim.x - 1)) {
            __hip_atomic_store(&bar[0], 0u, __ATOMIC_RELAXED, __HIP_MEMORY_SCOPE_AGENT);
            __hip_atomic_store(&bar[1], phase, __ATOMIC_RELEASE, __HIP_MEMORY_SCOPE_AGENT);
        } else {
            while (__hip_atomic_load(&bar[1], __ATOMIC_ACQUIRE, __HIP_MEMORY_SCOPE_AGENT) < phase) {
                __builtin_amdgcn_s_sleep(4);
            }
        }
        __threadfence();   // acquire: invalidate L1/L2 so this CU sees other blocks' writes
    }
    __syncthreads();
}

// ---------------- GEMM phase: out[N x FOUT] = A[N x 128] @ W[128 x FOUT], bf16 MFMA ----------------
// W staged once into LDS per phase; grid-stride over 64-row tiles (wave = 16 rows).
template <int FOUT>
static __device__ void gemm_phase(const void* __restrict__ Araw, int a_fp32,
                                  const void* __restrict__ Wraw, int in_fp32,
                                  unsigned short* __restrict__ out, int N,
                                  unsigned short* __restrict__ bt) {
    constexpr int K = 128;
    constexpr int NT = FOUT / 16;
    constexpr int LDB = K + 8;
    const int tid = threadIdx.x;

    constexpr int TOT4 = K * FOUT / 4;
    if (in_fp32) {
        const float* Wf = (const float*)Wraw;
        for (int i = tid; i < TOT4; i += 256) {
            int idx = i * 4;
            int k = idx / FOUT;
            int n = idx & (FOUT - 1);
            float4 v = *(const float4*)(const void*)(Wf + idx);
            bt[(n + 0) * LDB + k] = f2bf(v.x);
            bt[(n + 1) * LDB + k] = f2bf(v.y);
            bt[(n + 2) * LDB + k] = f2bf(v.z);
            bt[(n + 3) * LDB + k] = f2bf(v.w);
        }
    } else {
        const unsigned short* Ws = (const unsigned short*)Wraw;
        for (int i = tid; i < TOT4; i += 256) {
            int idx = i * 4;
            int k = idx / FOUT;
            int n = idx & (FOUT - 1);
            short4v v = *(const short4v*)(const void*)(Ws + idx);
#pragma unroll
            for (int j = 0; j < 4; j++) bt[(n + j) * LDB + k] = ((const unsigned short*)&v)[j];
        }
    }
    __syncthreads();

    const int wave = tid >> 6;
    const int lane = tid & 63;
    const int quad = lane >> 4;
    const int r16 = lane & 15;
    const int T = (N + 63) >> 6;   // 64-row tiles

    for (int tile = blockIdx.x; tile < T; tile += gridDim.x) {
        int arow = tile * 64 + wave * 16 + r16;
        if (arow > N - 1) arow = N - 1;
        short8 afrag[4];
        if (a_fp32) {
            const float* Ap = (const float*)Araw + (size_t)arow * K + quad * 8;
#pragma unroll
            for (int kk = 0; kk < 4; kk++) {
                float4 f0 = *(const float4*)(const void*)(Ap + kk * 32);
                float4 f1 = *(const float4*)(const void*)(Ap + kk * 32 + 4);
                short8 r;
                r[0] = (short)f2bf(f0.x); r[1] = (short)f2bf(f0.y);
                r[2] = (short)f2bf(f0.z); r[3] = (short)f2bf(f0.w);
                r[4] = (short)f2bf(f1.x); r[5] = (short)f2bf(f1.y);
                r[6] = (short)f2bf(f1.z); r[7] = (short)f2bf(f1.w);
                afrag[kk] = r;
            }
        } else {
            const unsigned short* Ap = (const unsigned short*)Araw + (size_t)arow * K + quad * 8;
#pragma unroll
            for (int kk = 0; kk < 4; kk++) afrag[kk] = *(const short8*)(const void*)(Ap + kk * 32);
        }

        f32x4 acc[NT];
#pragma unroll
        for (int nt = 0; nt < NT; nt++) acc[nt] = (f32x4){0.f, 0.f, 0.f, 0.f};
#pragma unroll
        for (int kk = 0; kk < 4; kk++) {
#pragma unroll
            for (int nt = 0; nt < NT; nt++) {
                short8 b = *(const short8*)(const void*)(&bt[(nt * 16 + r16) * LDB + kk * 32 + quad * 8]);
                acc[nt] = __builtin_amdgcn_mfma_f32_16x16x32_bf16(afrag[kk], b, acc[nt], 0, 0, 0);
            }
        }
        // C layout: col = lane&15, row = quad*4 + r. Pair cols via shfl_xor; even lanes store bf16x2.
#pragma unroll
        for (int nt = 0; nt < NT; nt++) {
#pragma unroll
            for (int r = 0; r < 4; r++) {
                float v = acc[nt][r];
                float o = __shfl_xor(v, 1, 64);
                int row = tile * 64 + wave * 16 + quad * 4 + r;
                if (((lane & 1) == 0) && row < N) {
                    __hip_bfloat162 pk;
                    pk.x = __float2bfloat16(v);
                    pk.y = __float2bfloat16(o);
                    *(__hip_bfloat162*)(out + (size_t)row * FOUT + nt * 16 + r16) = pk;
                }
            }
        }
    }
}

// ---------------- SpMM phase: wave per node, padded CSR, branch-free 16-deep ----------------
static __device__ void spmm128_phase(const int2* __restrict__ edgedat, const int2* __restrict__ rc,
                                     const __hip_bfloat162* __restrict__ Hin,
                                     __hip_bfloat162* __restrict__ Hout, int N,
                                     int gtid, int gsz, int lane) {
    int wgid = gtid >> 6, nw = gsz >> 6;
    const __hip_bfloat162* col = Hin + lane;
    for (int n = wgid; n < N; n += nw) {
        int2 r_ = rc[n];
        int start = __builtin_amdgcn_readfirstlane(r_.x);
        int lenp  = __builtin_amdgcn_readfirstlane(r_.y);
        float ax = 0.f, ay = 0.f;
        for (int j = 0; j < lenp; j += 16) {
            int2 ed[16];
#pragma unroll
            for (int u = 0; u < 16; u++) ed[u] = edgedat[start + j + u];
            __hip_bfloat162 hv[16];
#pragma unroll
            for (int u = 0; u < 16; u++) hv[u] = col[(size_t)ed[u].x * 64];
#pragma unroll
            for (int u = 0; u < 16; u++) {
                float w = __int_as_float(ed[u].y);
                ax += w * __bfloat162float(hv[u].x);
                ay += w * __bfloat162float(hv[u].y);
            }
        }
        __hip_bfloat162 pk;
        pk.x = __float2bfloat16(fmaxf(ax, 0.f));
        pk.y = __float2bfloat16(fmaxf(ay, 0.f));
        Hout[(size_t)n * 64 + lane] = pk;
    }
}

// ---------------- the persistent mega-kernel ----------------
__global__ __launch_bounds__(256, 4) void mega_kernel(
    const void* __restrict__ X, const int* __restrict__ ei,
    const void* __restrict__ W1, const void* __restrict__ W2, const void* __restrict__ W3,
    void* __restrict__ Out, int N, int E,
    unsigned* __restrict__ bar, int* __restrict__ total, int* __restrict__ counts,
    int2* __restrict__ rc, float* __restrict__ dinv, int* __restrict__ loff,
    int2* __restrict__ edgedat, unsigned short* __restrict__ HA, unsigned short* __restrict__ HB) {

    __shared__ __align__(16) unsigned short bt[128 * 136];

    const unsigned short* W1s = (const unsigned short*)W1;
    const int in_fp32 = sniff_fp32(W1s);
    const int is64 = sniff_is64((const unsigned int*)ei);
    const int gtid = blockIdx.x * 256 + threadIdx.x;
    const int gsz = gridDim.x * 256;
    const int lane = threadIdx.x & 63;

    // ---- P0: gemm1 (HA = X @ W1) then hist (counts pre-zeroed by host memset) ----
    gemm_phase<128>(X, in_fp32, W1, in_fp32, HA, N, bt);
    for (int e = gtid; e < E; e += gsz) {
        int d = is64 ? ei[2 * (size_t)E + 2 * e] : ei[(size_t)E + e];
        loff[e] = atomicAdd(&counts[d], 1);
    }
    gridbar(bar, 1);

    // ---- P1: alloc (dinv + padded segment alloc) + zero pad slots ----
    {
        int wgid = gtid >> 6, nw = gsz >> 6;
        for (int base = wgid * 64; base < N; base += nw * 64) {
            int n = base + lane;
            int c = (n < N) ? counts[n] : 0;
            if (n < N) {
                int d = (c < 1) ? 1 : c;
                dinv[n] = rsqrtf((float)d);
            }
            int lenp = (c + 15) & ~15;
            int incl = lenp;
#pragma unroll
            for (int off = 1; off < 64; off <<= 1) {
                int v = __shfl_up(incl, off, 64);
                if (lane >= off) incl += v;
            }
            int wavetot = __shfl(incl, 63, 64);
            int b2 = 0;
            if (lane == 0) b2 = atomicAdd(total, wavetot);
            b2 = __shfl(b2, 0, 64);
            if (n < N) {
                int start = b2 + incl - lenp;
                rc[n] = make_int2(start, lenp);
                for (int p = c; p < lenp; p++) edgedat[start + p] = make_int2(0, 0);  // pads: src=0,w=0
            }
        }
    }
    gridbar(bar, 2);

    // ---- P2: fill (atomic-free: rowptr + recorded local offset) ----
    for (int e = gtid; e < E; e += gsz) {
        int s, d;
        if (is64) {
            s = ei[2 * e];
            d = ei[2 * (size_t)E + 2 * e];
        } else {
            s = ei[e];
            d = ei[(size_t)E + e];
        }
        edgedat[rc[d].x + loff[e]] = make_int2(s, __float_as_int(dinv[s] * dinv[d]));
    }
    gridbar(bar, 3);

    // ---- P3: spmm1 (HB = relu(A HA)) ----
    spmm128_phase(edgedat, rc, (const __hip_bfloat162*)HA, (__hip_bfloat162*)HB, N, gtid, gsz, lane);
    gridbar(bar, 4);

    // ---- P4: gemm2 (HA = HB @ W2) ----
    gemm_phase<128>(HB, 0, W2, in_fp32, HA, N, bt);
    gridbar(bar, 5);

    // ---- P5: spmm2 (HB = relu(A HA)) ----
    spmm128_phase(edgedat, rc, (const __hip_bfloat162*)HA, (__hip_bfloat162*)HB, N, gtid, gsz, lane);
    gridbar(bar, 6);

    // ---- P6: gemm3 (HA[N,64] = HB @ W3) ----
    gemm_phase<64>(HB, 0, W3, in_fp32, HA, N, bt);
    gridbar(bar, 7);

    // ---- P7: spmm64 + relu + softmax -> Out ----
    {
        int wgid = gtid >> 6, nw = gsz >> 6;
        const unsigned short* col = HA + lane;
        for (int n = wgid; n < N; n += nw) {
            int2 r_ = rc[n];
            int start = __builtin_amdgcn_readfirstlane(r_.x);
            int lenp  = __builtin_amdgcn_readfirstlane(r_.y);
            float a = 0.f;
            for (int j = 0; j < lenp; j += 16) {
                int2 ed[16];
#pragma unroll
                for (int u = 0; u < 16; u++) ed[u] = edgedat[start + j + u];
                float hv[16];
#pragma unroll
                for (int u = 0; u < 16; u++) hv[u] = bfbits2f(col[(size_t)ed[u].x * 64]);
#pragma unroll
                for (int u = 0; u < 16; u++) a += __int_as_float(ed[u].y) * hv[u];
            }
            a = fmaxf(a, 0.f);
            float m = a;
#pragma unroll
            for (int off = 32; off > 0; off >>= 1) m = fmaxf(m, __shfl_xor(m, off, 64));
            float e = __expf(a - m);
            float s = e;
#pragma unroll
            for (int off = 32; off > 0; off >>= 1) s += __shfl_xor(s, off, 64);
            float r = e / s;
            if (in_fp32) {
                ((float*)Out)[(size_t)n * 64 + lane] = r;
            } else {
                ((unsigned short*)Out)[(size_t)n * 64 + lane] = f2bf(r);
            }
        }
    }
}

// ---------------- launch: 1 memset + 1 kernel ----------------
extern "C" void kernel_launch(void* const* d_in, const int* in_sizes, int n_in,
                              void* d_out, int out_size, void* d_ws, size_t ws_size,
                              hipStream_t stream) {
    const void* X  = d_in[0];                       // [N,128] bf16 or fp32
    const int*  ei = (const int*)d_in[1];           // [2,E] int32 or int64
    const void* W1 = d_in[2];                       // [128,128]
    const void* W2 = d_in[3];                       // [128,128]
    const void* W3 = d_in[4];                       // [128,64]

    const int N = in_sizes[0] / 128;   // 50000
    const int E = in_sizes[1] / 2;     // 800000

    const size_t edgecap = (size_t)E + 16 * (size_t)N + 64;

    char* ws = (char*)d_ws;
    size_t off = 0;
    unsigned* bar = (unsigned*)(ws + off);          // bar[0]=count, bar[1]=flag
    int* total    = (int*)(ws + off + 8);
    off += 64;
    int* counts   = (int*)(ws + off);   off += ws_align((size_t)N * 4);
    const size_t zero_bytes = off;     // bar + total + counts
    int2* rc      = (int2*)(ws + off);  off += ws_align((size_t)N * 8);
    float* dinv   = (float*)(ws + off); off += ws_align((size_t)N * 4);
    int* loff     = (int*)(ws + off);   off += ws_align((size_t)E * 4);
    int2* edgedat = (int2*)(ws + off);  off += ws_align(edgecap * 8);
    unsigned short* HA = (unsigned short*)(ws + off); off += ws_align((size_t)N * 128 * 2);
    unsigned short* HB = (unsigned short*)(ws + off); off += ws_align((size_t)N * 128 * 2);

    hipMemsetAsync(d_ws, 0, zero_bytes, stream);

    mega_kernel<<<NBLK, 256, 0, stream>>>(X, ei, W1, W2, W3, d_out, N, E,
                                          bar, total, counts, rc, dinv, loff,
                                          edgedat, HA, HB);
}

// Round 9
// 284.078 us; speedup vs baseline: 6.5698x; 6.5698x over previous
//
#include <hip/hip_runtime.h>
#include <hip/hip_bf16.h>

typedef __attribute__((ext_vector_type(8))) short short8;
typedef __attribute__((ext_vector_type(4))) short short4v;
typedef __attribute__((ext_vector_type(4))) float f32x4;

static inline size_t ws_align(size_t x) { return (x + 511) & ~((size_t)511); }

static __device__ inline unsigned short f2bf(float f) {
    __hip_bfloat16 h = __float2bfloat16(f);
    return __builtin_bit_cast(unsigned short, h);
}
static __device__ inline float bfbits2f(unsigned short u) {
    unsigned x = ((unsigned)u) << 16;
    return __builtin_bit_cast(float, x);
}

// ---------------- inline dtype sniffing (per-wave ballot) ----------------
static __device__ inline int sniff_fp32(const unsigned short* __restrict__ w1) {
    int i = threadIdx.x & 63;
    unsigned e = (w1[2 * i] >> 7) & 0xFF;
    unsigned long long m = __ballot(e >= 100 && e <= 130);
    return (__popcll(m) < 48) ? 1 : 0;
}
static __device__ inline int sniff_is64(const unsigned int* __restrict__ ei) {
    int i = threadIdx.x & 63;
    unsigned long long m = __ballot(ei[2 * i + 1] == 0u);
    return (__popcll(m) >= 48) ? 1 : 0;
}

// ---------------- CSR build ----------------
__global__ void hist_kernel(const int* __restrict__ ei,
                            int* __restrict__ counts, int* __restrict__ loff, int E) {
    int is64 = sniff_is64((const unsigned int*)ei);
    int e = blockIdx.x * blockDim.x + threadIdx.x;
    if (e < E) {
        int d = is64 ? ei[2 * (size_t)E + 2 * e] : ei[(size_t)E + e];
        loff[e] = atomicAdd(&counts[d], 1);
    }
}

// fused: dinv + padded segment allocation (pad to 8) + pad-slot writes (src=0,w=0).
__global__ __launch_bounds__(256) void alloc_kernel(const int* __restrict__ counts,
                                                    float* __restrict__ dinv,
                                                    int2* __restrict__ rc,
                                                    int2* __restrict__ edgedat,
                                                    int* __restrict__ total, int N) {
    int n = blockIdx.x * blockDim.x + threadIdx.x;
    int lane = threadIdx.x & 63;
    int c = (n < N) ? counts[n] : 0;
    if (n < N) {
        int d = (c < 1) ? 1 : c;
        dinv[n] = rsqrtf((float)d);
    }
    int lenp = (c + 7) & ~7;
    int incl = lenp;
#pragma unroll
    for (int off = 1; off < 64; off <<= 1) {
        int v = __shfl_up(incl, off, 64);
        if (lane >= off) incl += v;
    }
    int wavetot = __shfl(incl, 63, 64);
    int base = 0;
    if (lane == 0) base = atomicAdd(total, wavetot);
    base = __shfl(base, 0, 64);
    if (n < N) {
        int start = base + incl - lenp;
        rc[n] = make_int2(start, lenp);
        for (int p = c; p < lenp; p++) edgedat[start + p] = make_int2(0, 0);
    }
}

// atomic-free fill: position = segment start + recorded local offset.
__global__ void fill_kernel(const int* __restrict__ ei,
                            const float* __restrict__ dinv, const int2* __restrict__ rc,
                            const int* __restrict__ loff, int2* __restrict__ edgedat, int E) {
    int is64 = sniff_is64((const unsigned int*)ei);
    int e = blockIdx.x * blockDim.x + threadIdx.x;
    if (e < E) {
        int s, d;
        if (is64) {
            s = ei[2 * e];
            d = ei[2 * (size_t)E + 2 * e];
        } else {
            s = ei[e];
            d = ei[(size_t)E + e];
        }
        int pos = rc[d].x + loff[e];
        float wt = dinv[s] * dinv[d];
        edgedat[pos] = make_int2(s, __float_as_int(wt));
    }
}

// ---------------- GEMM: out[N x FOUT] = A[N x 128] @ W[128 x FOUT], bf16 MFMA ----------------
// 256 threads = 4 waves; each wave computes 2 row-tiles of 16 -> 128 rows/block. (r4-verified)
template <int FOUT>
__global__ __launch_bounds__(256) void gemm_kernel(const void* __restrict__ Araw, int a_follows,
                                                   const void* __restrict__ Wraw,
                                                   const unsigned short* __restrict__ w1sniff,
                                                   unsigned short* __restrict__ out, int Nrows) {
    constexpr int K = 128;
    constexpr int NT = FOUT / 16;
    constexpr int LDB = K + 8;
    __shared__ __align__(16) unsigned short bt[FOUT * LDB];  // bt[n][k] = W[k][n]

    const int tid = threadIdx.x;
    const int in_fp32 = sniff_fp32(w1sniff);
    const int a_fp32 = a_follows & in_fp32;

    constexpr int TOT4 = K * FOUT / 4;
    if (in_fp32) {
        const float* Wf = (const float*)Wraw;
        for (int i = tid; i < TOT4; i += 256) {
            int idx = i * 4;
            int k = idx / FOUT;
            int n = idx & (FOUT - 1);
            float4 v = *(const float4*)(const void*)(Wf + idx);
            bt[(n + 0) * LDB + k] = f2bf(v.x);
            bt[(n + 1) * LDB + k] = f2bf(v.y);
            bt[(n + 2) * LDB + k] = f2bf(v.z);
            bt[(n + 3) * LDB + k] = f2bf(v.w);
        }
    } else {
        const unsigned short* Ws = (const unsigned short*)Wraw;
        for (int i = tid; i < TOT4; i += 256) {
            int idx = i * 4;
            int k = idx / FOUT;
            int n = idx & (FOUT - 1);
            short4v v = *(const short4v*)(const void*)(Ws + idx);
#pragma unroll
            for (int j = 0; j < 4; j++) bt[(n + j) * LDB + k] = ((const unsigned short*)&v)[j];
        }
    }

    const int wave = tid >> 6;
    const int lane = tid & 63;
    const int quad = lane >> 4;
    const int r16 = lane & 15;

    short8 afrag[2][4];
#pragma unroll
    for (int t = 0; t < 2; t++) {
        int arow = blockIdx.x * 128 + t * 64 + wave * 16 + r16;
        if (arow > Nrows - 1) arow = Nrows - 1;
        if (a_fp32) {
            const float* Ap = (const float*)Araw + (size_t)arow * K + quad * 8;
#pragma unroll
            for (int kk = 0; kk < 4; kk++) {
                float4 f0 = *(const float4*)(const void*)(Ap + kk * 32);
                float4 f1 = *(const float4*)(const void*)(Ap + kk * 32 + 4);
                short8 r;
                r[0] = (short)f2bf(f0.x); r[1] = (short)f2bf(f0.y);
                r[2] = (short)f2bf(f0.z); r[3] = (short)f2bf(f0.w);
                r[4] = (short)f2bf(f1.x); r[5] = (short)f2bf(f1.y);
                r[6] = (short)f2bf(f1.z); r[7] = (short)f2bf(f1.w);
                afrag[t][kk] = r;
            }
        } else {
            const unsigned short* Ap = (const unsigned short*)Araw + (size_t)arow * K + quad * 8;
#pragma unroll
            for (int kk = 0; kk < 4; kk++) afrag[t][kk] = *(const short8*)(const void*)(Ap + kk * 32);
        }
    }

    __syncthreads();

    f32x4 acc[2][NT];
#pragma unroll
    for (int t = 0; t < 2; t++)
#pragma unroll
        for (int nt = 0; nt < NT; nt++) acc[t][nt] = (f32x4){0.f, 0.f, 0.f, 0.f};

#pragma unroll
    for (int kk = 0; kk < 4; kk++) {
#pragma unroll
        for (int nt = 0; nt < NT; nt++) {
            short8 b = *(const short8*)(const void*)(&bt[(nt * 16 + r16) * LDB + kk * 32 + quad * 8]);
#pragma unroll
            for (int t = 0; t < 2; t++)
                acc[t][nt] = __builtin_amdgcn_mfma_f32_16x16x32_bf16(afrag[t][kk], b, acc[t][nt], 0, 0, 0);
        }
    }

    // C layout: col = lane&15, row = quad*4 + r. Pack col pairs via shfl_xor; even lanes store bf16x2.
#pragma unroll
    for (int t = 0; t < 2; t++) {
#pragma unroll
        for (int nt = 0; nt < NT; nt++) {
#pragma unroll
            for (int r = 0; r < 4; r++) {
                float v = acc[t][nt][r];
                float o = __shfl_xor(v, 1, 64);
                int row = blockIdx.x * 128 + t * 64 + wave * 16 + quad * 4 + r;
                if (((lane & 1) == 0) && row < Nrows) {
                    __hip_bfloat162 pk;
                    pk.x = __float2bfloat16(v);
                    pk.y = __float2bfloat16(o);
                    *(__hip_bfloat162*)(out + (size_t)row * FOUT + nt * 16 + r16) = pk;
                }
            }
        }
    }
}

// ---------------- SpMM F=128: wave per node, TWO column passes (64 cols each) ----------------
// Pass working set = N*64*2B = 6.4MB (vs 12.8) -> better per-XCD L2 residency.
// Gather per edge per pass: 64 lanes x 2B = 128B contiguous. Branch-free 8-deep (padded CSR).
__global__ __launch_bounds__(256) void spmm128_kernel(const int2* __restrict__ edgedat,
                                                      const int2* __restrict__ rc,
                                                      const unsigned short* __restrict__ Hin,
                                                      unsigned short* __restrict__ Hout, int N) {
    int wid = (blockIdx.x * 256 + threadIdx.x) >> 6;
    if (wid >= N) return;
    int lane = threadIdx.x & 63;
    int2 r_ = rc[wid];
    int start = __builtin_amdgcn_readfirstlane(r_.x);
    int lenp  = __builtin_amdgcn_readfirstlane(r_.y);

#pragma unroll
    for (int p = 0; p < 2; p++) {
        const unsigned short* col = Hin + p * 64 + lane;
        float a = 0.f;
        for (int j = 0; j < lenp; j += 8) {
            int2 ed[8];
#pragma unroll
            for (int u = 0; u < 8; u++) ed[u] = edgedat[start + j + u];
            float hv[8];
#pragma unroll
            for (int u = 0; u < 8; u++) hv[u] = bfbits2f(col[(size_t)ed[u].x * 128]);
#pragma unroll
            for (int u = 0; u < 8; u++) a += __int_as_float(ed[u].y) * hv[u];
        }
        Hout[(size_t)wid * 128 + p * 64 + lane] = f2bf(fmaxf(a, 0.f));
    }
}

// F=64 + relu + softmax over the 64 lanes (64 classes). Branch-free 8-deep.
__global__ __launch_bounds__(256) void spmm64_softmax_kernel(const int2* __restrict__ edgedat,
                                                             const int2* __restrict__ rc,
                                                             const unsigned short* __restrict__ Hin,
                                                             const unsigned short* __restrict__ w1sniff,
                                                             void* __restrict__ Out, int N) {
    int out_fp32 = sniff_fp32(w1sniff);
    int wid = (blockIdx.x * 256 + threadIdx.x) >> 6;
    if (wid >= N) return;
    int lane = threadIdx.x & 63;
    int2 r_ = rc[wid];
    int start = __builtin_amdgcn_readfirstlane(r_.x);
    int lenp  = __builtin_amdgcn_readfirstlane(r_.y);
    const unsigned short* col = Hin + lane;

    float a = 0.f;
    for (int j = 0; j < lenp; j += 8) {
        int2 ed[8];
#pragma unroll
        for (int u = 0; u < 8; u++) ed[u] = edgedat[start + j + u];
        float hv[8];
#pragma unroll
        for (int u = 0; u < 8; u++) hv[u] = bfbits2f(col[(size_t)ed[u].x * 64]);
#pragma unroll
        for (int u = 0; u < 8; u++) a += __int_as_float(ed[u].y) * hv[u];
    }
    a = fmaxf(a, 0.f);   // relu
    float m = a;
#pragma unroll
    for (int off = 32; off > 0; off >>= 1) m = fmaxf(m, __shfl_xor(m, off, 64));
    float e = __expf(a - m);
    float s = e;
#pragma unroll
    for (int off = 32; off > 0; off >>= 1) s += __shfl_xor(s, off, 64);
    float r = e / s;
    if (out_fp32) {
        ((float*)Out)[(size_t)wid * 64 + lane] = r;
    } else {
        ((unsigned short*)Out)[(size_t)wid * 64 + lane] = f2bf(r);
    }
}

// ---------------- launch ----------------
extern "C" void kernel_launch(void* const* d_in, const int* in_sizes, int n_in,
                              void* d_out, int out_size, void* d_ws, size_t ws_size,
                              hipStream_t stream) {
    const void* X  = d_in[0];                       // [N,128] bf16 or fp32
    const int*  ei = (const int*)d_in[1];           // [2,E] int32 or int64
    const void* W1 = d_in[2];                       // [128,128]
    const void* W2 = d_in[3];                       // [128,128]
    const void* W3 = d_in[4];                       // [128,64]
    const unsigned short* W1s = (const unsigned short*)W1;

    const int N = in_sizes[0] / 128;   // 50000
    const int E = in_sizes[1] / 2;     // 800000

    const size_t edgecap = (size_t)E + 8 * (size_t)N + 64;  // padded-CSR slot capacity

    char* ws = (char*)d_ws;
    size_t off = 0;
    int* counts = (int*)(ws + off);   off += ws_align((size_t)N * 4);
    int* total  = (int*)(ws + off);   off += ws_align(64);
    const size_t zero_bytes = off;    // counts + total need zeroing
    int2* rc      = (int2*)(ws + off);  off += ws_align((size_t)N * 8);
    float* dinv   = (float*)(ws + off); off += ws_align((size_t)N * 4);
    int* loff     = (int*)(ws + off);   off += ws_align((size_t)E * 4);
    int2* edgedat = (int2*)(ws + off);  off += ws_align(edgecap * 8);
    unsigned short* HA = (unsigned short*)(ws + off); off += ws_align((size_t)N * 128 * 2);
    unsigned short* HB = (unsigned short*)(ws + off); off += ws_align((size_t)N * 128 * 2);

    hipMemsetAsync(d_ws, 0, zero_bytes, stream);

    hist_kernel<<<(E + 255) / 256, 256, 0, stream>>>(ei, counts, loff, E);
    alloc_kernel<<<(N + 255) / 256, 256, 0, stream>>>(counts, dinv, rc, edgedat, total, N);
    fill_kernel<<<(E + 255) / 256, 256, 0, stream>>>(ei, dinv, rc, loff, edgedat, E);

    const int gblocks = (N + 127) / 128;
    const int sblocks = ((size_t)N * 64 + 255) / 256;   // one wave per node

    // layer 1: HA = X @ W1 ; HB = relu(A_norm HA)
    gemm_kernel<128><<<gblocks, 256, 0, stream>>>(X, 1, W1, W1s, HA, N);
    spmm128_kernel<<<sblocks, 256, 0, stream>>>(edgedat, rc, HA, HB, N);
    // layer 2
    gemm_kernel<128><<<gblocks, 256, 0, stream>>>(HB, 0, W2, W1s, HA, N);
    spmm128_kernel<<<sblocks, 256, 0, stream>>>(edgedat, rc, HA, HB, N);
    // layer 3 (F_out = 64) + relu + softmax
    gemm_kernel<64><<<gblocks, 256, 0, stream>>>(HB, 0, W3, W1s, HA, N);
    spmm64_softmax_kernel<<<sblocks, 256, 0, stream>>>(edgedat, rc, HA, W1s, d_out, N);
}